// Round 1
// baseline (2187.852 us; speedup 1.0000x reference)
//
#include <hip/hip_runtime.h>
#include <stdint.h>

#define DD 4096
#define HH 11008
#define RANK 16
#define NTOK 4096

typedef __attribute__((ext_vector_type(8))) short short8;
typedef __attribute__((ext_vector_type(4))) float f32x4;

static __device__ __forceinline__ unsigned short f2bf(float f) {
    union { float f; uint32_t u; } x; x.f = f;
    uint32_t r = (x.u + 0x7fffu + ((x.u >> 16) & 1u)) >> 16;
    return (unsigned short)r;
}
static __device__ __forceinline__ float bf2f(unsigned short s) {
    union { uint32_t u; float f; } x; x.u = ((uint32_t)s) << 16;
    return x.f;
}

// ---------------- RMSNorm: fp32 [4096][4096] -> bf16 ----------------
__global__ __launch_bounds__(256) void rmsnorm_kernel(
    const float* __restrict__ data, const float* __restrict__ nw,
    unsigned short* __restrict__ xb) {
    const int row = blockIdx.x;
    const int t = threadIdx.x;
    const float4* dr = (const float4*)(data + (size_t)row * DD);
    float4 v[4];
    float ss = 0.f;
#pragma unroll
    for (int i = 0; i < 4; i++) {
        v[i] = dr[t + 256 * i];
        ss += v[i].x * v[i].x + v[i].y * v[i].y + v[i].z * v[i].z + v[i].w * v[i].w;
    }
#pragma unroll
    for (int off = 32; off > 0; off >>= 1) ss += __shfl_down(ss, off);
    __shared__ float red[4];
    if ((t & 63) == 0) red[t >> 6] = ss;
    __syncthreads();
    float total = red[0] + red[1] + red[2] + red[3];
    float inv = rsqrtf(total / (float)DD + 1e-5f);
    const float4* wr = (const float4*)nw;
    uint2* xo = (uint2*)(xb + (size_t)row * DD);
#pragma unroll
    for (int i = 0; i < 4; i++) {
        float4 w = wr[t + 256 * i];
        union { unsigned short u[4]; uint2 q; } p;
        p.u[0] = f2bf(v[i].x * inv * w.x);
        p.u[1] = f2bf(v[i].y * inv * w.y);
        p.u[2] = f2bf(v[i].z * inv * w.z);
        p.u[3] = f2bf(v[i].w * inv * w.w);
        xo[t + 256 * i] = p.q;
    }
}

// ------------- Transpose + convert: W [K][N] fp32 -> WT [N][K] bf16 -------------
__global__ __launch_bounds__(256) void transpose_cvt(
    const float* __restrict__ W, unsigned short* __restrict__ WT, int K, int N) {
    __shared__ float tile[64][65];
    const int t = threadIdx.x;
    const int n0 = blockIdx.x * 64, k0 = blockIdx.y * 64;
    const int cn = (t & 15) * 4, rk = t >> 4;
#pragma unroll
    for (int p = 0; p < 4; p++) {
        int kk = rk + p * 16;
        float4 v = *(const float4*)(W + (size_t)(k0 + kk) * N + n0 + cn);
        tile[kk][cn] = v.x; tile[kk][cn + 1] = v.y;
        tile[kk][cn + 2] = v.z; tile[kk][cn + 3] = v.w;
    }
    __syncthreads();
    const int n = t >> 2, ks = (t & 3) * 16;
    union { unsigned short u[16]; uint4 q[2]; } pk;
#pragma unroll
    for (int j = 0; j < 16; j++) pk.u[j] = f2bf(tile[ks + j][n]);
    uint4* dst = (uint4*)(WT + (size_t)(n0 + n) * K + k0 + ks);
    dst[0] = pk.q[0];
    dst[1] = pk.q[1];
}

// ------------- LoRA rank projection: t1/t3 = xb @ A1/A3 (per adapter) -------------
__global__ __launch_bounds__(256) void lora_x_kernel(
    const unsigned short* __restrict__ xb, const float* __restrict__ A1,
    const float* __restrict__ A3, float* __restrict__ t1, float* __restrict__ t3) {
    const int row0 = blockIdx.x * 4;
    const int a = row0 >> 10;
    const int t = threadIdx.x;
    __shared__ unsigned short xs[4][DD];
    __shared__ float p1[16][16][4], p3[16][16][4];
#pragma unroll
    for (int i = 0; i < 8; i++) {
        int c = t + 256 * i;  // < 2048
        int r = c >> 9, col = (c & 511) * 8;
        *(uint4*)&xs[r][col] = *(const uint4*)(xb + (size_t)(row0 + r) * DD + col);
    }
    __syncthreads();
    const int rr = t & 15, chunk = t >> 4;
    const float* A1p = A1 + (size_t)a * DD * RANK + rr;
    const float* A3p = A3 + (size_t)a * DD * RANK + rr;
    float acc1[4] = {0, 0, 0, 0}, acc3[4] = {0, 0, 0, 0};
    for (int d = chunk * 256; d < chunk * 256 + 256; d++) {
        float a1 = A1p[d * RANK];
        float a3 = A3p[d * RANK];
#pragma unroll
        for (int r = 0; r < 4; r++) {
            float xv = bf2f(xs[r][d]);
            acc1[r] += xv * a1;
            acc3[r] += xv * a3;
        }
    }
#pragma unroll
    for (int r = 0; r < 4; r++) { p1[chunk][rr][r] = acc1[r]; p3[chunk][rr][r] = acc3[r]; }
    __syncthreads();
    if (t < 64) {
        int r = t & 3, rk = t >> 2;
        float s1 = 0.f, s3 = 0.f;
        for (int c = 0; c < 16; c++) { s1 += p1[c][rk][r]; s3 += p3[c][rk][r]; }
        t1[(size_t)(row0 + r) * RANK + rk] = s1;
        t3[(size_t)(row0 + r) * RANK + rk] = s3;
    }
}

// ------------- LoRA rank projection: t2 = act @ A2 (per adapter) -------------
__global__ __launch_bounds__(256) void lora_act_kernel(
    const unsigned short* __restrict__ act, const float* __restrict__ A2,
    float* __restrict__ t2) {
    const int row0 = blockIdx.x * 2;
    const int a = row0 >> 10;
    const int t = threadIdx.x;
    __shared__ unsigned short xs[2][HH];
    __shared__ float p2[16][16][2];
#pragma unroll
    for (int i = 0; i < 11; i++) {
        int c = t + 256 * i;  // need < 2752
        if (c < 2752) {
            int r = c / 1376, col = (c % 1376) * 8;
            *(uint4*)&xs[r][col] = *(const uint4*)(act + (size_t)(row0 + r) * HH + col);
        }
    }
    __syncthreads();
    const int rr = t & 15, chunk = t >> 4;
    const float* A2p = A2 + (size_t)a * HH * RANK + rr;
    float acc0 = 0.f, acc1v = 0.f;
    for (int d = chunk * 688; d < chunk * 688 + 688; d++) {
        float a2 = A2p[d * RANK];
        acc0 += bf2f(xs[0][d]) * a2;
        acc1v += bf2f(xs[1][d]) * a2;
    }
    p2[chunk][rr][0] = acc0;
    p2[chunk][rr][1] = acc1v;
    __syncthreads();
    if (t < 32) {
        int r = t & 1, rk = t >> 1;
        float s = 0.f;
        for (int c = 0; c < 16; c++) s += p2[c][rk][r];
        t2[(size_t)(row0 + r) * RANK + rk] = s;
    }
}

// ------------- G1: act = silu(x@W1 + t1@B1) * (x@W3 + t3@B3) -------------
__global__ __launch_bounds__(256, 2) void gemm1_kernel(
    const unsigned short* __restrict__ xb, const unsigned short* __restrict__ W1T,
    const unsigned short* __restrict__ W3T, const float* __restrict__ t1,
    const float* __restrict__ t3, const float* __restrict__ B1f,
    const float* __restrict__ B3f, unsigned short* __restrict__ act) {
    const int m0 = blockIdx.x * 128, n0 = blockIdx.y * 128;
    const int a = m0 >> 10;
    const int t = threadIdx.x;
    const int lane = t & 63, w = t >> 6, wm = w & 1, wn = w >> 1;
    const int lr = lane & 15, q = lane >> 4;
    __shared__ __align__(16) unsigned short Al[128 * 40];
    __shared__ __align__(16) unsigned short B1l[128 * 40];
    __shared__ __align__(16) unsigned short B3l[128 * 40];
    f32x4 acc1[4][4], acc3[4][4];
#pragma unroll
    for (int mi = 0; mi < 4; mi++)
#pragma unroll
        for (int nj = 0; nj < 4; nj++) {
            acc1[mi][nj] = (f32x4){0.f, 0.f, 0.f, 0.f};
            acc3[mi][nj] = (f32x4){0.f, 0.f, 0.f, 0.f};
        }

    for (int kt = 0; kt < DD / 32; kt++) {
        const int kof = kt * 32;
#pragma unroll
        for (int i = 0; i < 2; i++) {
            int idx = t + 256 * i;
            int arow = idx >> 2, cg = (idx & 3) * 8;
            uint4 va = *(const uint4*)(xb + (size_t)(m0 + arow) * DD + kof + cg);
            uint4 vb1 = *(const uint4*)(W1T + (size_t)(n0 + arow) * DD + kof + cg);
            uint4 vb3 = *(const uint4*)(W3T + (size_t)(n0 + arow) * DD + kof + cg);
            *(uint4*)&Al[arow * 40 + cg] = va;
            *(uint4*)&B1l[arow * 40 + cg] = vb1;
            *(uint4*)&B3l[arow * 40 + cg] = vb3;
        }
        __syncthreads();
        short8 av[4];
#pragma unroll
        for (int mi = 0; mi < 4; mi++)
            av[mi] = *reinterpret_cast<const short8*>(&Al[(wm * 64 + mi * 16 + lr) * 40 + q * 8]);
#pragma unroll
        for (int nj = 0; nj < 4; nj++) {
            short8 b1 = *reinterpret_cast<const short8*>(&B1l[(wn * 64 + nj * 16 + lr) * 40 + q * 8]);
            short8 b3 = *reinterpret_cast<const short8*>(&B3l[(wn * 64 + nj * 16 + lr) * 40 + q * 8]);
#pragma unroll
            for (int mi = 0; mi < 4; mi++) {
                acc1[mi][nj] = __builtin_amdgcn_mfma_f32_16x16x32_bf16(av[mi], b1, acc1[mi][nj], 0, 0, 0);
                acc3[mi][nj] = __builtin_amdgcn_mfma_f32_16x16x32_bf16(av[mi], b3, acc3[mi][nj], 0, 0, 0);
            }
        }
        __syncthreads();
    }

    // --- LoRA K-extension iteration 1: acc1 += t1_tile (K=16, zero-padded) @ B1^T ---
    {
        const int arow = t >> 1, hf = t & 1;
        uint4 z; z.x = z.y = z.z = z.w = 0u;
        const float4* tp = (const float4*)(t1 + (size_t)(m0 + arow) * RANK + hf * 8);
        float4 u0 = tp[0], u1 = tp[1];
        union { unsigned short u[8]; uint4 q; } pa;
        pa.u[0] = f2bf(u0.x); pa.u[1] = f2bf(u0.y); pa.u[2] = f2bf(u0.z); pa.u[3] = f2bf(u0.w);
        pa.u[4] = f2bf(u1.x); pa.u[5] = f2bf(u1.y); pa.u[6] = f2bf(u1.z); pa.u[7] = f2bf(u1.w);
        *(uint4*)&Al[arow * 40 + hf * 8] = pa.q;
        *(uint4*)&Al[arow * 40 + 16 + hf * 8] = z;
        union { unsigned short u[8]; uint4 q; } pb;
#pragma unroll
        for (int j = 0; j < 8; j++)
            pb.u[j] = f2bf(B1f[((size_t)a * RANK + hf * 8 + j) * HH + n0 + arow]);
        *(uint4*)&B1l[arow * 40 + hf * 8] = pb.q;
        *(uint4*)&B1l[arow * 40 + 16 + hf * 8] = z;
        __syncthreads();
        short8 av[4];
#pragma unroll
        for (int mi = 0; mi < 4; mi++)
            av[mi] = *reinterpret_cast<const short8*>(&Al[(wm * 64 + mi * 16 + lr) * 40 + q * 8]);
#pragma unroll
        for (int nj = 0; nj < 4; nj++) {
            short8 b1 = *reinterpret_cast<const short8*>(&B1l[(wn * 64 + nj * 16 + lr) * 40 + q * 8]);
#pragma unroll
            for (int mi = 0; mi < 4; mi++)
                acc1[mi][nj] = __builtin_amdgcn_mfma_f32_16x16x32_bf16(av[mi], b1, acc1[mi][nj], 0, 0, 0);
        }
        __syncthreads();
        // --- LoRA K-extension iteration 2: acc3 += t3_tile @ B3^T ---
        const float4* tp3 = (const float4*)(t3 + (size_t)(m0 + arow) * RANK + hf * 8);
        float4 w0 = tp3[0], w1 = tp3[1];
        pa.u[0] = f2bf(w0.x); pa.u[1] = f2bf(w0.y); pa.u[2] = f2bf(w0.z); pa.u[3] = f2bf(w0.w);
        pa.u[4] = f2bf(w1.x); pa.u[5] = f2bf(w1.y); pa.u[6] = f2bf(w1.z); pa.u[7] = f2bf(w1.w);
        *(uint4*)&Al[arow * 40 + hf * 8] = pa.q;
        *(uint4*)&Al[arow * 40 + 16 + hf * 8] = z;
#pragma unroll
        for (int j = 0; j < 8; j++)
            pb.u[j] = f2bf(B3f[((size_t)a * RANK + hf * 8 + j) * HH + n0 + arow]);
        *(uint4*)&B3l[arow * 40 + hf * 8] = pb.q;
        *(uint4*)&B3l[arow * 40 + 16 + hf * 8] = z;
        __syncthreads();
#pragma unroll
        for (int mi = 0; mi < 4; mi++)
            av[mi] = *reinterpret_cast<const short8*>(&Al[(wm * 64 + mi * 16 + lr) * 40 + q * 8]);
#pragma unroll
        for (int nj = 0; nj < 4; nj++) {
            short8 b3 = *reinterpret_cast<const short8*>(&B3l[(wn * 64 + nj * 16 + lr) * 40 + q * 8]);
#pragma unroll
            for (int mi = 0; mi < 4; mi++)
                acc3[mi][nj] = __builtin_amdgcn_mfma_f32_16x16x32_bf16(av[mi], b3, acc3[mi][nj], 0, 0, 0);
        }
    }

    // --- epilogue: silu(h1)*h3 -> bf16 ---
#pragma unroll
    for (int mi = 0; mi < 4; mi++)
#pragma unroll
        for (int nj = 0; nj < 4; nj++)
#pragma unroll
            for (int rg = 0; rg < 4; rg++) {
                int row = wm * 64 + mi * 16 + q * 4 + rg;
                int col = wn * 64 + nj * 16 + lr;
                float h1 = acc1[mi][nj][rg];
                float h3 = acc3[mi][nj][rg];
                float sig = 1.f / (1.f + __expf(-h1));
                float o = h1 * sig * h3;
                act[(size_t)(m0 + row) * HH + n0 + col] = f2bf(o);
            }
}

// ------------- G2: out = act@W2 + t2@B2 -------------
__global__ __launch_bounds__(256, 2) void gemm2_kernel(
    const unsigned short* __restrict__ actb, const unsigned short* __restrict__ W2T,
    const float* __restrict__ t2, const float* __restrict__ B2f,
    float* __restrict__ out) {
    const int m0 = blockIdx.x * 128, n0 = blockIdx.y * 128;
    const int a = m0 >> 10;
    const int t = threadIdx.x;
    const int lane = t & 63, w = t >> 6, wm = w & 1, wn = w >> 1;
    const int lr = lane & 15, q = lane >> 4;
    __shared__ __align__(16) unsigned short Al[128 * 40];
    __shared__ __align__(16) unsigned short Bl[128 * 40];
    f32x4 acc[4][4];
#pragma unroll
    for (int mi = 0; mi < 4; mi++)
#pragma unroll
        for (int nj = 0; nj < 4; nj++) acc[mi][nj] = (f32x4){0.f, 0.f, 0.f, 0.f};

    for (int kt = 0; kt < HH / 32; kt++) {
        const int kof = kt * 32;
#pragma unroll
        for (int i = 0; i < 2; i++) {
            int idx = t + 256 * i;
            int arow = idx >> 2, cg = (idx & 3) * 8;
            uint4 va = *(const uint4*)(actb + (size_t)(m0 + arow) * HH + kof + cg);
            uint4 vb = *(const uint4*)(W2T + (size_t)(n0 + arow) * HH + kof + cg);
            *(uint4*)&Al[arow * 40 + cg] = va;
            *(uint4*)&Bl[arow * 40 + cg] = vb;
        }
        __syncthreads();
        short8 av[4];
#pragma unroll
        for (int mi = 0; mi < 4; mi++)
            av[mi] = *reinterpret_cast<const short8*>(&Al[(wm * 64 + mi * 16 + lr) * 40 + q * 8]);
#pragma unroll
        for (int nj = 0; nj < 4; nj++) {
            short8 b = *reinterpret_cast<const short8*>(&Bl[(wn * 64 + nj * 16 + lr) * 40 + q * 8]);
#pragma unroll
            for (int mi = 0; mi < 4; mi++)
                acc[mi][nj] = __builtin_amdgcn_mfma_f32_16x16x32_bf16(av[mi], b, acc[mi][nj], 0, 0, 0);
        }
        __syncthreads();
    }

    // --- LoRA K-extension: acc += t2_tile @ B2^T ---
    {
        const int arow = t >> 1, hf = t & 1;
        uint4 z; z.x = z.y = z.z = z.w = 0u;
        const float4* tp = (const float4*)(t2 + (size_t)(m0 + arow) * RANK + hf * 8);
        float4 u0 = tp[0], u1 = tp[1];
        union { unsigned short u[8]; uint4 q; } pa;
        pa.u[0] = f2bf(u0.x); pa.u[1] = f2bf(u0.y); pa.u[2] = f2bf(u0.z); pa.u[3] = f2bf(u0.w);
        pa.u[4] = f2bf(u1.x); pa.u[5] = f2bf(u1.y); pa.u[6] = f2bf(u1.z); pa.u[7] = f2bf(u1.w);
        *(uint4*)&Al[arow * 40 + hf * 8] = pa.q;
        *(uint4*)&Al[arow * 40 + 16 + hf * 8] = z;
        union { unsigned short u[8]; uint4 q; } pb;
#pragma unroll
        for (int j = 0; j < 8; j++)
            pb.u[j] = f2bf(B2f[((size_t)a * RANK + hf * 8 + j) * DD + n0 + arow]);
        *(uint4*)&Bl[arow * 40 + hf * 8] = pb.q;
        *(uint4*)&Bl[arow * 40 + 16 + hf * 8] = z;
        __syncthreads();
        short8 av[4];
#pragma unroll
        for (int mi = 0; mi < 4; mi++)
            av[mi] = *reinterpret_cast<const short8*>(&Al[(wm * 64 + mi * 16 + lr) * 40 + q * 8]);
#pragma unroll
        for (int nj = 0; nj < 4; nj++) {
            short8 b = *reinterpret_cast<const short8*>(&Bl[(wn * 64 + nj * 16 + lr) * 40 + q * 8]);
#pragma unroll
            for (int mi = 0; mi < 4; mi++)
                acc[mi][nj] = __builtin_amdgcn_mfma_f32_16x16x32_bf16(av[mi], b, acc[mi][nj], 0, 0, 0);
        }
    }

#pragma unroll
    for (int mi = 0; mi < 4; mi++)
#pragma unroll
        for (int nj = 0; nj < 4; nj++)
#pragma unroll
            for (int rg = 0; rg < 4; rg++) {
                int row = wm * 64 + mi * 16 + q * 4 + rg;
                int col = wn * 64 + nj * 16 + lr;
                out[(size_t)(m0 + row) * DD + n0 + col] = acc[mi][nj][rg];
            }
}

// ---------------- launch ----------------
extern "C" void kernel_launch(void* const* d_in, const int* in_sizes, int n_in,
                              void* d_out, int out_size, void* d_ws, size_t ws_size,
                              hipStream_t stream) {
    const float* data = (const float*)d_in[0];
    const float* norm_w = (const float*)d_in[1];
    const float* W1 = (const float*)d_in[2];
    const float* W3 = (const float*)d_in[3];
    const float* W2 = (const float*)d_in[4];
    const float* A1 = (const float*)d_in[5];
    const float* B1 = (const float*)d_in[6];
    const float* A3 = (const float*)d_in[7];
    const float* B3 = (const float*)d_in[8];
    const float* A2 = (const float*)d_in[9];
    const float* B2 = (const float*)d_in[10];
    float* out = (float*)d_out;

    char* ws = (char*)d_ws;
    const size_t WT_BYTES = (size_t)DD * HH * 2;         // 90,177,536
    unsigned short* W1T = (unsigned short*)(ws + 0);
    unsigned short* W3T = (unsigned short*)(ws + WT_BYTES);
    unsigned short* W2T = (unsigned short*)(ws + 0);     // reuse after gemm1
    unsigned short* xb  = (unsigned short*)(ws + 2 * WT_BYTES);
    unsigned short* act = (unsigned short*)(ws + 2 * WT_BYTES + (size_t)NTOK * DD * 2);
    float* t1 = (float*)(ws + 2 * WT_BYTES + (size_t)NTOK * DD * 2 + (size_t)NTOK * HH * 2);
    float* t3 = t1 + (size_t)NTOK * RANK;
    float* t2 = t3 + (size_t)NTOK * RANK;

    rmsnorm_kernel<<<NTOK, 256, 0, stream>>>(data, norm_w, xb);
    transpose_cvt<<<dim3(HH / 64, DD / 64), 256, 0, stream>>>(W1, W1T, DD, HH);
    transpose_cvt<<<dim3(HH / 64, DD / 64), 256, 0, stream>>>(W3, W3T, DD, HH);
    lora_x_kernel<<<NTOK / 4, 256, 0, stream>>>(xb, A1, A3, t1, t3);
    gemm1_kernel<<<dim3(32, HH / 128), 256, 0, stream>>>(xb, W1T, W3T, t1, t3, B1, B3, act);
    transpose_cvt<<<dim3(DD / 64, HH / 64), 256, 0, stream>>>(W2, W2T, HH, DD);
    lora_act_kernel<<<NTOK / 2, 256, 0, stream>>>(act, A2, t2);
    gemm2_kernel<<<dim3(32, DD / 128), 256, 0, stream>>>(act, W2T, t2, B2, out);
}

// Round 2
// 2047.241 us; speedup vs baseline: 1.0687x; 1.0687x over previous
//
#include <hip/hip_runtime.h>
#include <stdint.h>

#define DD 4096
#define HH 11008
#define RANK 16
#define NTOK 4096

typedef __attribute__((ext_vector_type(8))) short short8;
typedef __attribute__((ext_vector_type(4))) float f32x4;

static __device__ __forceinline__ unsigned short f2bf(float f) {
    union { float f; uint32_t u; } x; x.f = f;
    uint32_t r = (x.u + 0x7fffu + ((x.u >> 16) & 1u)) >> 16;
    return (unsigned short)r;
}
static __device__ __forceinline__ float bf2f(unsigned short s) {
    union { uint32_t u; float f; } x; x.u = ((uint32_t)s) << 16;
    return x.f;
}

// async global->LDS, 16B per lane; lds dest = wave-uniform base + lane*16
static __device__ __forceinline__ void gl_lds16(const unsigned short* g, unsigned short* l) {
    __builtin_amdgcn_global_load_lds(
        (const __attribute__((address_space(1))) unsigned int*)g,
        (__attribute__((address_space(3))) unsigned int*)l, 16, 0, 0);
}

// ---------------- RMSNorm: fp32 [4096][4096] -> bf16 ----------------
__global__ __launch_bounds__(256) void rmsnorm_kernel(
    const float* __restrict__ data, const float* __restrict__ nw,
    unsigned short* __restrict__ xb) {
    const int row = blockIdx.x;
    const int t = threadIdx.x;
    const float4* dr = (const float4*)(data + (size_t)row * DD);
    float4 v[4];
    float ss = 0.f;
#pragma unroll
    for (int i = 0; i < 4; i++) {
        v[i] = dr[t + 256 * i];
        ss += v[i].x * v[i].x + v[i].y * v[i].y + v[i].z * v[i].z + v[i].w * v[i].w;
    }
#pragma unroll
    for (int off = 32; off > 0; off >>= 1) ss += __shfl_down(ss, off);
    __shared__ float red[4];
    if ((t & 63) == 0) red[t >> 6] = ss;
    __syncthreads();
    float total = red[0] + red[1] + red[2] + red[3];
    float inv = rsqrtf(total / (float)DD + 1e-5f);
    const float4* wr = (const float4*)nw;
    uint2* xo = (uint2*)(xb + (size_t)row * DD);
#pragma unroll
    for (int i = 0; i < 4; i++) {
        float4 w = wr[t + 256 * i];
        union { unsigned short u[4]; uint2 q; } p;
        p.u[0] = f2bf(v[i].x * inv * w.x);
        p.u[1] = f2bf(v[i].y * inv * w.y);
        p.u[2] = f2bf(v[i].z * inv * w.z);
        p.u[3] = f2bf(v[i].w * inv * w.w);
        xo[t + 256 * i] = p.q;
    }
}

// ------------- Transpose + convert: W [K][N] fp32 -> WT [N][K] bf16 -------------
__global__ __launch_bounds__(256) void transpose_cvt(
    const float* __restrict__ W, unsigned short* __restrict__ WT, int K, int N) {
    __shared__ float tile[64][65];
    const int t = threadIdx.x;
    const int n0 = blockIdx.x * 64, k0 = blockIdx.y * 64;
    const int cn = (t & 15) * 4, rk = t >> 4;
#pragma unroll
    for (int p = 0; p < 4; p++) {
        int kk = rk + p * 16;
        float4 v = *(const float4*)(W + (size_t)(k0 + kk) * N + n0 + cn);
        tile[kk][cn] = v.x; tile[kk][cn + 1] = v.y;
        tile[kk][cn + 2] = v.z; tile[kk][cn + 3] = v.w;
    }
    __syncthreads();
    const int n = t >> 2, ks = (t & 3) * 16;
    union { unsigned short u[16]; uint4 q[2]; } pk;
#pragma unroll
    for (int j = 0; j < 16; j++) pk.u[j] = f2bf(tile[ks + j][n]);
    uint4* dst = (uint4*)(WT + (size_t)(n0 + n) * K + k0 + ks);
    dst[0] = pk.q[0];
    dst[1] = pk.q[1];
}

// ------------- LoRA rank projection: t1/t3 = xb @ A1/A3 (16 tokens/block) -------------
__global__ __launch_bounds__(256) void lora_x_kernel(
    const unsigned short* __restrict__ xb, const float* __restrict__ A1,
    const float* __restrict__ A3, float* __restrict__ t1, float* __restrict__ t3) {
    const int row0 = blockIdx.x * 16;       // 256 blocks
    const int a = row0 >> 10;
    const int t = threadIdx.x;
    const int tok = t >> 4, rk = t & 15;
    __shared__ unsigned short xs[16][264];  // +8 pad: breaks 4-way token conflict
    __shared__ float a1s[256][16];
    __shared__ float a3s[256][16];
    float acc1 = 0.f, acc3 = 0.f;
    for (int c = 0; c < DD / 256; c++) {
        const int d0 = c * 256;
        __syncthreads();
#pragma unroll
        for (int i = 0; i < 2; i++) {
            int idx = t + 256 * i;
            int r = idx >> 5, cs = (idx & 31) * 8;
            *(uint4*)&xs[r][cs] = *(const uint4*)(xb + (size_t)(row0 + r) * DD + d0 + cs);
        }
        const float* A1c = A1 + ((size_t)a * DD + d0) * RANK;
        const float* A3c = A3 + ((size_t)a * DD + d0) * RANK;
#pragma unroll
        for (int i = 0; i < 4; i++) {
            int j = (t + 256 * i) * 4;
            *(float4*)&((float*)a1s)[j] = *(const float4*)(A1c + j);
            *(float4*)&((float*)a3s)[j] = *(const float4*)(A3c + j);
        }
        __syncthreads();
#pragma unroll 8
        for (int d = 0; d < 256; d++) {
            float xv = bf2f(xs[tok][d]);
            acc1 += xv * a1s[d][rk];
            acc3 += xv * a3s[d][rk];
        }
    }
    t1[(size_t)(row0 + tok) * RANK + rk] = acc1;
    t3[(size_t)(row0 + tok) * RANK + rk] = acc3;
}

// ------------- LoRA rank projection: t2 = act @ A2 (16 tokens/block) -------------
__global__ __launch_bounds__(256) void lora_act_kernel(
    const unsigned short* __restrict__ act, const float* __restrict__ A2,
    float* __restrict__ t2) {
    const int row0 = blockIdx.x * 16;       // 256 blocks
    const int a = row0 >> 10;
    const int t = threadIdx.x;
    const int tok = t >> 4, rk = t & 15;
    __shared__ unsigned short xs[16][264];
    __shared__ float a2s[256][16];
    float acc = 0.f;
    for (int c = 0; c < HH / 256; c++) {   // 43 chunks
        const int d0 = c * 256;
        __syncthreads();
#pragma unroll
        for (int i = 0; i < 2; i++) {
            int idx = t + 256 * i;
            int r = idx >> 5, cs = (idx & 31) * 8;
            *(uint4*)&xs[r][cs] = *(const uint4*)(act + (size_t)(row0 + r) * HH + d0 + cs);
        }
        const float* A2c = A2 + ((size_t)a * HH + d0) * RANK;
#pragma unroll
        for (int i = 0; i < 4; i++) {
            int j = (t + 256 * i) * 4;
            *(float4*)&((float*)a2s)[j] = *(const float4*)(A2c + j);
        }
        __syncthreads();
#pragma unroll 8
        for (int d = 0; d < 256; d++) {
            acc += bf2f(xs[tok][d]) * a2s[d][rk];
        }
    }
    t2[(size_t)(row0 + tok) * RANK + rk] = acc;
}

// ------------- G1: act = silu(x@W1 + t1@B1) * (x@W3 + t3@B3) -------------
__global__ __launch_bounds__(256, 3) void gemm1_kernel(
    const unsigned short* __restrict__ xb, const unsigned short* __restrict__ W1T,
    const unsigned short* __restrict__ W3T, const float* __restrict__ t1,
    const float* __restrict__ t3, const float* __restrict__ B1f,
    const float* __restrict__ B3f, unsigned short* __restrict__ act) {
    const int m0 = blockIdx.x * 128, n0 = blockIdx.y * 128;
    const int a = m0 >> 10;
    const int t = threadIdx.x;
    const int lane = t & 63, w = t >> 6, wm = w & 1, wn = w >> 1;
    const int lr = lane & 15, q = lane >> 4;
    const int srow = lane >> 2;          // staging row within 16
    const int scol = (lane & 3) * 8;     // staging col (shorts)
    __shared__ __align__(16) unsigned short Al[128 * 32];
    __shared__ __align__(16) unsigned short B1l[128 * 32];
    __shared__ __align__(16) unsigned short B3l[128 * 32];
    f32x4 acc1[4][4], acc3[4][4];
#pragma unroll
    for (int mi = 0; mi < 4; mi++)
#pragma unroll
        for (int nj = 0; nj < 4; nj++) {
            acc1[mi][nj] = (f32x4){0.f, 0.f, 0.f, 0.f};
            acc3[mi][nj] = (f32x4){0.f, 0.f, 0.f, 0.f};
        }

    const unsigned short* gA  = xb  + (size_t)(m0 + w * 32 + srow) * DD + scol;
    const unsigned short* gB1 = W1T + (size_t)(n0 + w * 32 + srow) * DD + scol;
    const unsigned short* gB3 = W3T + (size_t)(n0 + w * 32 + srow) * DD + scol;
    unsigned short* lA  = &Al[w * 1024];
    unsigned short* lB1 = &B1l[w * 1024];
    unsigned short* lB3 = &B3l[w * 1024];

    for (int kt = 0; kt < DD / 32; kt++) {
        const int kof = kt * 32;
        gl_lds16(gA  + kof,                    lA);
        gl_lds16(gA  + kof + (size_t)16 * DD,  lA + 512);
        gl_lds16(gB1 + kof,                    lB1);
        gl_lds16(gB1 + kof + (size_t)16 * DD,  lB1 + 512);
        gl_lds16(gB3 + kof,                    lB3);
        gl_lds16(gB3 + kof + (size_t)16 * DD,  lB3 + 512);
        __syncthreads();
        short8 av[4];
#pragma unroll
        for (int mi = 0; mi < 4; mi++)
            av[mi] = *reinterpret_cast<const short8*>(&Al[(wm * 64 + mi * 16 + lr) * 32 + q * 8]);
#pragma unroll
        for (int nj = 0; nj < 4; nj++) {
            short8 b1 = *reinterpret_cast<const short8*>(&B1l[(wn * 64 + nj * 16 + lr) * 32 + q * 8]);
            short8 b3 = *reinterpret_cast<const short8*>(&B3l[(wn * 64 + nj * 16 + lr) * 32 + q * 8]);
#pragma unroll
            for (int mi = 0; mi < 4; mi++) {
                acc1[mi][nj] = __builtin_amdgcn_mfma_f32_16x16x32_bf16(av[mi], b1, acc1[mi][nj], 0, 0, 0);
                acc3[mi][nj] = __builtin_amdgcn_mfma_f32_16x16x32_bf16(av[mi], b3, acc3[mi][nj], 0, 0, 0);
            }
        }
        __syncthreads();
    }

    // --- LoRA K-extension iteration 1: acc1 += t1_tile (K=16, zero-padded) @ B1^T ---
    {
        const int arow = t >> 1, hf = t & 1;
        uint4 z; z.x = z.y = z.z = z.w = 0u;
        const float4* tp = (const float4*)(t1 + (size_t)(m0 + arow) * RANK + hf * 8);
        float4 u0 = tp[0], u1 = tp[1];
        union { unsigned short u[8]; uint4 q; } pa;
        pa.u[0] = f2bf(u0.x); pa.u[1] = f2bf(u0.y); pa.u[2] = f2bf(u0.z); pa.u[3] = f2bf(u0.w);
        pa.u[4] = f2bf(u1.x); pa.u[5] = f2bf(u1.y); pa.u[6] = f2bf(u1.z); pa.u[7] = f2bf(u1.w);
        *(uint4*)&Al[arow * 32 + hf * 8] = pa.q;
        *(uint4*)&Al[arow * 32 + 16 + hf * 8] = z;
        union { unsigned short u[8]; uint4 q; } pb;
#pragma unroll
        for (int j = 0; j < 8; j++)
            pb.u[j] = f2bf(B1f[((size_t)a * RANK + hf * 8 + j) * HH + n0 + arow]);
        *(uint4*)&B1l[arow * 32 + hf * 8] = pb.q;
        *(uint4*)&B1l[arow * 32 + 16 + hf * 8] = z;
        __syncthreads();
        short8 av[4];
#pragma unroll
        for (int mi = 0; mi < 4; mi++)
            av[mi] = *reinterpret_cast<const short8*>(&Al[(wm * 64 + mi * 16 + lr) * 32 + q * 8]);
#pragma unroll
        for (int nj = 0; nj < 4; nj++) {
            short8 b1 = *reinterpret_cast<const short8*>(&B1l[(wn * 64 + nj * 16 + lr) * 32 + q * 8]);
#pragma unroll
            for (int mi = 0; mi < 4; mi++)
                acc1[mi][nj] = __builtin_amdgcn_mfma_f32_16x16x32_bf16(av[mi], b1, acc1[mi][nj], 0, 0, 0);
        }
        __syncthreads();
        // --- LoRA K-extension iteration 2: acc3 += t3_tile @ B3^T ---
        const float4* tp3 = (const float4*)(t3 + (size_t)(m0 + arow) * RANK + hf * 8);
        float4 w0 = tp3[0], w1 = tp3[1];
        pa.u[0] = f2bf(w0.x); pa.u[1] = f2bf(w0.y); pa.u[2] = f2bf(w0.z); pa.u[3] = f2bf(w0.w);
        pa.u[4] = f2bf(w1.x); pa.u[5] = f2bf(w1.y); pa.u[6] = f2bf(w1.z); pa.u[7] = f2bf(w1.w);
        *(uint4*)&Al[arow * 32 + hf * 8] = pa.q;
        *(uint4*)&Al[arow * 32 + 16 + hf * 8] = z;
#pragma unroll
        for (int j = 0; j < 8; j++)
            pb.u[j] = f2bf(B3f[((size_t)a * RANK + hf * 8 + j) * HH + n0 + arow]);
        *(uint4*)&B3l[arow * 32 + hf * 8] = pb.q;
        *(uint4*)&B3l[arow * 32 + 16 + hf * 8] = z;
        __syncthreads();
#pragma unroll
        for (int mi = 0; mi < 4; mi++)
            av[mi] = *reinterpret_cast<const short8*>(&Al[(wm * 64 + mi * 16 + lr) * 32 + q * 8]);
#pragma unroll
        for (int nj = 0; nj < 4; nj++) {
            short8 b3 = *reinterpret_cast<const short8*>(&B3l[(wn * 64 + nj * 16 + lr) * 32 + q * 8]);
#pragma unroll
            for (int mi = 0; mi < 4; mi++)
                acc3[mi][nj] = __builtin_amdgcn_mfma_f32_16x16x32_bf16(av[mi], b3, acc3[mi][nj], 0, 0, 0);
        }
    }

    // --- epilogue: silu(h1)*h3 -> bf16 ---
#pragma unroll
    for (int mi = 0; mi < 4; mi++)
#pragma unroll
        for (int nj = 0; nj < 4; nj++)
#pragma unroll
            for (int rg = 0; rg < 4; rg++) {
                int row = wm * 64 + mi * 16 + q * 4 + rg;
                int col = wn * 64 + nj * 16 + lr;
                float h1 = acc1[mi][nj][rg];
                float h3 = acc3[mi][nj][rg];
                float sig = 1.f / (1.f + __expf(-h1));
                float o = h1 * sig * h3;
                act[(size_t)(m0 + row) * HH + n0 + col] = f2bf(o);
            }
}

// ------------- G2: out = act@W2 + t2@B2 -------------
__global__ __launch_bounds__(256, 3) void gemm2_kernel(
    const unsigned short* __restrict__ actb, const unsigned short* __restrict__ W2T,
    const float* __restrict__ t2, const float* __restrict__ B2f,
    float* __restrict__ out) {
    const int m0 = blockIdx.x * 128, n0 = blockIdx.y * 128;
    const int a = m0 >> 10;
    const int t = threadIdx.x;
    const int lane = t & 63, w = t >> 6, wm = w & 1, wn = w >> 1;
    const int lr = lane & 15, q = lane >> 4;
    const int srow = lane >> 2;
    const int scol = (lane & 3) * 8;
    __shared__ __align__(16) unsigned short Al[128 * 32];
    __shared__ __align__(16) unsigned short Bl[128 * 32];
    f32x4 acc[4][4];
#pragma unroll
    for (int mi = 0; mi < 4; mi++)
#pragma unroll
        for (int nj = 0; nj < 4; nj++) acc[mi][nj] = (f32x4){0.f, 0.f, 0.f, 0.f};

    const unsigned short* gA = actb + (size_t)(m0 + w * 32 + srow) * HH + scol;
    const unsigned short* gB = W2T  + (size_t)(n0 + w * 32 + srow) * HH + scol;
    unsigned short* lA = &Al[w * 1024];
    unsigned short* lB = &Bl[w * 1024];

    for (int kt = 0; kt < HH / 32; kt++) {
        const int kof = kt * 32;
        gl_lds16(gA + kof,                   lA);
        gl_lds16(gA + kof + (size_t)16 * HH, lA + 512);
        gl_lds16(gB + kof,                   lB);
        gl_lds16(gB + kof + (size_t)16 * HH, lB + 512);
        __syncthreads();
        short8 av[4];
#pragma unroll
        for (int mi = 0; mi < 4; mi++)
            av[mi] = *reinterpret_cast<const short8*>(&Al[(wm * 64 + mi * 16 + lr) * 32 + q * 8]);
#pragma unroll
        for (int nj = 0; nj < 4; nj++) {
            short8 b = *reinterpret_cast<const short8*>(&Bl[(wn * 64 + nj * 16 + lr) * 32 + q * 8]);
#pragma unroll
            for (int mi = 0; mi < 4; mi++)
                acc[mi][nj] = __builtin_amdgcn_mfma_f32_16x16x32_bf16(av[mi], b, acc[mi][nj], 0, 0, 0);
        }
        __syncthreads();
    }

    // --- LoRA K-extension: acc += t2_tile @ B2^T ---
    {
        const int arow = t >> 1, hf = t & 1;
        uint4 z; z.x = z.y = z.z = z.w = 0u;
        const float4* tp = (const float4*)(t2 + (size_t)(m0 + arow) * RANK + hf * 8);
        float4 u0 = tp[0], u1 = tp[1];
        union { unsigned short u[8]; uint4 q; } pa;
        pa.u[0] = f2bf(u0.x); pa.u[1] = f2bf(u0.y); pa.u[2] = f2bf(u0.z); pa.u[3] = f2bf(u0.w);
        pa.u[4] = f2bf(u1.x); pa.u[5] = f2bf(u1.y); pa.u[6] = f2bf(u1.z); pa.u[7] = f2bf(u1.w);
        *(uint4*)&Al[arow * 32 + hf * 8] = pa.q;
        *(uint4*)&Al[arow * 32 + 16 + hf * 8] = z;
        union { unsigned short u[8]; uint4 q; } pb;
#pragma unroll
        for (int j = 0; j < 8; j++)
            pb.u[j] = f2bf(B2f[((size_t)a * RANK + hf * 8 + j) * DD + n0 + arow]);
        *(uint4*)&Bl[arow * 32 + hf * 8] = pb.q;
        *(uint4*)&Bl[arow * 32 + 16 + hf * 8] = z;
        __syncthreads();
        short8 av[4];
#pragma unroll
        for (int mi = 0; mi < 4; mi++)
            av[mi] = *reinterpret_cast<const short8*>(&Al[(wm * 64 + mi * 16 + lr) * 32 + q * 8]);
#pragma unroll
        for (int nj = 0; nj < 4; nj++) {
            short8 b = *reinterpret_cast<const short8*>(&Bl[(wn * 64 + nj * 16 + lr) * 32 + q * 8]);
#pragma unroll
            for (int mi = 0; mi < 4; mi++)
                acc[mi][nj] = __builtin_amdgcn_mfma_f32_16x16x32_bf16(av[mi], b, acc[mi][nj], 0, 0, 0);
        }
    }

#pragma unroll
    for (int mi = 0; mi < 4; mi++)
#pragma unroll
        for (int nj = 0; nj < 4; nj++)
#pragma unroll
            for (int rg = 0; rg < 4; rg++) {
                int row = wm * 64 + mi * 16 + q * 4 + rg;
                int col = wn * 64 + nj * 16 + lr;
                out[(size_t)(m0 + row) * DD + n0 + col] = acc[mi][nj][rg];
            }
}

// ---------------- launch ----------------
extern "C" void kernel_launch(void* const* d_in, const int* in_sizes, int n_in,
                              void* d_out, int out_size, void* d_ws, size_t ws_size,
                              hipStream_t stream) {
    const float* data = (const float*)d_in[0];
    const float* norm_w = (const float*)d_in[1];
    const float* W1 = (const float*)d_in[2];
    const float* W3 = (const float*)d_in[3];
    const float* W2 = (const float*)d_in[4];
    const float* A1 = (const float*)d_in[5];
    const float* B1 = (const float*)d_in[6];
    const float* A3 = (const float*)d_in[7];
    const float* B3 = (const float*)d_in[8];
    const float* A2 = (const float*)d_in[9];
    const float* B2 = (const float*)d_in[10];
    float* out = (float*)d_out;

    char* ws = (char*)d_ws;
    const size_t WT_BYTES = (size_t)DD * HH * 2;         // 90,177,536
    unsigned short* W1T = (unsigned short*)(ws + 0);
    unsigned short* W3T = (unsigned short*)(ws + WT_BYTES);
    unsigned short* W2T = (unsigned short*)(ws + 0);     // reuse after gemm1
    unsigned short* xb  = (unsigned short*)(ws + 2 * WT_BYTES);
    unsigned short* act = (unsigned short*)(ws + 2 * WT_BYTES + (size_t)NTOK * DD * 2);
    float* t1 = (float*)(ws + 2 * WT_BYTES + (size_t)NTOK * DD * 2 + (size_t)NTOK * HH * 2);
    float* t3 = t1 + (size_t)NTOK * RANK;
    float* t2 = t3 + (size_t)NTOK * RANK;

    rmsnorm_kernel<<<NTOK, 256, 0, stream>>>(data, norm_w, xb);
    transpose_cvt<<<dim3(HH / 64, DD / 64), 256, 0, stream>>>(W1, W1T, DD, HH);
    transpose_cvt<<<dim3(HH / 64, DD / 64), 256, 0, stream>>>(W3, W3T, DD, HH);
    lora_x_kernel<<<NTOK / 16, 256, 0, stream>>>(xb, A1, A3, t1, t3);
    gemm1_kernel<<<dim3(32, HH / 128), 256, 0, stream>>>(xb, W1T, W3T, t1, t3, B1, B3, act);
    transpose_cvt<<<dim3(DD / 64, HH / 64), 256, 0, stream>>>(W2, W2T, HH, DD);
    lora_act_kernel<<<NTOK / 16, 256, 0, stream>>>(act, A2, t2);
    gemm2_kernel<<<dim3(32, DD / 128), 256, 0, stream>>>(act, W2T, t2, B2, out);
}